// Round 14
// baseline (441.959 us; speedup 1.0000x reference)
//
#include <hip/hip_runtime.h>
#include <hip/hip_fp16.h>
#include <hip/hip_bf16.h>

// PGNN layer for MI355X (gfx950).
//   u = feature @ W_u + b_u ; v = feature @ W_v + b_v       [N,64] each
//   msg[e] = v[dst[e]] + u[src[e]] * sp_dist[e]
//   msgs = relu(msg[anchor_eid]) -> [N,K,64]
//   out_position = msgs @ W_out + b_out  [N,K];  out_structure = mean_k [N,64]
// N=50000, K=64, E=3.2M. d_out = out_position ++ out_structure.
//
// R14 = R13 resubmitted (infra failure, never measured).
// R13 vs R12 (evidence: pass time invariant across 2B/8B/16B gathers at
// 512 cyc/wave = 4 cyc per distinct 64B line-touch per CU; 25.6M touches
// -> 166us. Gathers miss L1 (3.2MB slice >> 32KB, random) -> suspect
// L1-fill/MSHR rate): uvT gathers made NON-TEMPORAL (L1 bypass). If the
// wall is L1 fill, service rate rises toward the L2 port rate.
// Null result pre-commits next lever: fp8 uvT + 2 slices (halve touches).

#define IN_DIM 256
#define OUT_DIM 64
#define KANCH 64

typedef float vfloat4 __attribute__((ext_vector_type(4)));
typedef unsigned int vuint4 __attribute__((ext_vector_type(4)));

// ---------------- merge + pos-init (fused launch) --------------------------
// Blocks [0, mergeBlocks): meta[i] = src|dst<<17|half(sp)<<34 (ids < 2^17).
// Blocks [mergeBlocks, ...): out_pos[0..M) = b_out[0] (float4 stores).
__global__ __launch_bounds__(256) void pgnn_merge_init_kernel(
    const int* __restrict__ src, const int* __restrict__ dst,
    const float* __restrict__ sp, unsigned long long* __restrict__ meta, int E,
    float* __restrict__ out_pos, const float* __restrict__ b_out, int M,
    int mergeBlocks)
{
    if ((int)blockIdx.x < mergeBlocks) {
        int i = blockIdx.x * 256 + threadIdx.x;
        if (i >= E) return;
        unsigned long long pk =
              (unsigned long long)(unsigned)__builtin_nontemporal_load(&src[i])
            | ((unsigned long long)(unsigned)__builtin_nontemporal_load(&dst[i]) << 17)
            | ((unsigned long long)__half_as_ushort(
                   __float2half_rn(__builtin_nontemporal_load(&sp[i]))) << 34);
        __builtin_nontemporal_store(pk, &meta[i]);
    } else {
        const float bo = b_out[0];
        int i4 = (blockIdx.x - mergeBlocks) * 256 + threadIdx.x;
        int base = i4 * 4;
        if (base + 3 < M) {
            vfloat4 s = {bo, bo, bo, bo};
            __builtin_nontemporal_store(s, reinterpret_cast<vfloat4*>(&out_pos[base]));
        } else {
            for (int i = base; i < M; ++i) out_pos[i] = bo;
        }
    }
}

// ---------------- fused: proj GEMM (dbuf) + pack ---------------------------
#define PAa 68
#define PBb 132
#define TILEF (16 * PAa + 16 * PBb)   // floats per buffer = 3200
__global__ __launch_bounds__(256) void pgnn_fused_kernel(
    const float* __restrict__ feature,
    const float* __restrict__ Wu, const float* __restrict__ bu,
    const float* __restrict__ Wv, const float* __restrict__ bv,
    __half* __restrict__ uvT,
    const int* __restrict__ aeid,
    const unsigned long long* __restrict__ meta,
    unsigned long long* __restrict__ packed,
    int N, int M, int projBlocks, int packBlocks)
{
    __shared__ float smem[2 * TILEF];
    const int tid = threadIdx.x;

    if ((int)blockIdx.x < projBlocks) {
        const int row0 = blockIdx.x * 64;
        const int tr = tid >> 4;
        const int tc = tid & 15;
        const int mA = tid >> 2, c4A = tid & 3;
        const int grA = row0 + mA;

        float accU[4][4], accV[4][4];
        #pragma unroll
        for (int i = 0; i < 4; ++i)
            #pragma unroll
            for (int j = 0; j < 4; ++j) { accU[i][j] = 0.f; accV[i][j] = 0.f; }

        float4 ra, rb0, rb1;
        auto load_tile = [&](int k0) {
            ra = make_float4(0.f, 0.f, 0.f, 0.f);
            if (grA < N)
                ra = *reinterpret_cast<const float4*>(
                        &feature[(size_t)grA * IN_DIM + k0 + c4A * 4]);
            {
                int f = tid, kk = f >> 5, c4 = f & 31;
                rb0 = (c4 < 16)
                    ? *reinterpret_cast<const float4*>(&Wu[(k0 + kk) * OUT_DIM + c4 * 4])
                    : *reinterpret_cast<const float4*>(&Wv[(k0 + kk) * OUT_DIM + (c4 - 16) * 4]);
            }
            {
                int f = tid + 256, kk = f >> 5, c4 = f & 31;
                rb1 = (c4 < 16)
                    ? *reinterpret_cast<const float4*>(&Wu[(k0 + kk) * OUT_DIM + c4 * 4])
                    : *reinterpret_cast<const float4*>(&Wv[(k0 + kk) * OUT_DIM + (c4 - 16) * 4]);
            }
        };
        auto store_tile = [&](float* buf) {
            buf[(c4A * 4 + 0) * PAa + mA] = ra.x;
            buf[(c4A * 4 + 1) * PAa + mA] = ra.y;
            buf[(c4A * 4 + 2) * PAa + mA] = ra.z;
            buf[(c4A * 4 + 3) * PAa + mA] = ra.w;
            float* sB = buf + 16 * PAa;
            {
                int f = tid, kk = f >> 5, c4 = f & 31;
                *reinterpret_cast<float4*>(&sB[kk * PBb + c4 * 4]) = rb0;
            }
            {
                int f = tid + 256, kk = f >> 5, c4 = f & 31;
                *reinterpret_cast<float4*>(&sB[kk * PBb + c4 * 4]) = rb1;
            }
        };

        load_tile(0);
        store_tile(smem);
        __syncthreads();

        for (int s = 0; s < 16; ++s) {
            const int cur = s & 1;
            if (s < 15) load_tile((s + 1) * 16);
            const float* buf = smem + cur * TILEF;
            const float* sB  = buf + 16 * PAa;
            #pragma unroll
            for (int k = 0; k < 16; ++k) {
                float4 a  = *reinterpret_cast<const float4*>(&buf[k * PAa + tr * 4]);
                float4 b0 = *reinterpret_cast<const float4*>(&sB[k * PBb + tc * 4]);
                float4 b1 = *reinterpret_cast<const float4*>(&sB[k * PBb + 64 + tc * 4]);
                float av[4]  = {a.x, a.y, a.z, a.w};
                float bu4[4] = {b0.x, b0.y, b0.z, b0.w};
                float bv4[4] = {b1.x, b1.y, b1.z, b1.w};
                #pragma unroll
                for (int i = 0; i < 4; ++i)
                    #pragma unroll
                    for (int j = 0; j < 4; ++j) {
                        accU[i][j] = fmaf(av[i], bu4[j], accU[i][j]);
                        accV[i][j] = fmaf(av[i], bv4[j], accV[i][j]);
                    }
            }
            if (s < 15) store_tile(smem + (cur ^ 1) * TILEF);
            __syncthreads();
        }

        const int q  = tc >> 2;
        const int i0 = (tc & 3) * 4;
        float bU[4], bV[4];
        #pragma unroll
        for (int j = 0; j < 4; ++j) { bU[j] = bu[tc * 4 + j]; bV[j] = bv[tc * 4 + j]; }
        #pragma unroll
        for (int i = 0; i < 4; ++i) {
            int gr = row0 + tr * 4 + i;
            if (gr >= N) continue;
            __half* rowp = uvT + ((size_t)q * N + gr) * 32;
            __half2 hu0 = __floats2half2_rn(accU[i][0] + bU[0], accU[i][1] + bU[1]);
            __half2 hu1 = __floats2half2_rn(accU[i][2] + bU[2], accU[i][3] + bU[3]);
            __half2 hv0 = __floats2half2_rn(accV[i][0] + bV[0], accV[i][1] + bV[1]);
            __half2 hv1 = __floats2half2_rn(accV[i][2] + bV[2], accV[i][3] + bV[3]);
            *reinterpret_cast<__half2*>(rowp + i0)          = hu0;
            *reinterpret_cast<__half2*>(rowp + i0 + 2)      = hu1;
            *reinterpret_cast<__half2*>(rowp + 16 + i0)     = hv0;
            *reinterpret_cast<__half2*>(rowp + 16 + i0 + 2) = hv1;
        }
    } else {
        const int stride = packBlocks * 256;
        int i = (blockIdx.x - projBlocks) * 256 + tid;
        while (i + 7 * stride < M) {
            int e[8];
            #pragma unroll
            for (int b = 0; b < 8; ++b)
                e[b] = __builtin_nontemporal_load(&aeid[i + b * stride]);
            unsigned long long m[8];
            #pragma unroll
            for (int b = 0; b < 8; ++b)
                m[b] = __builtin_nontemporal_load(&meta[e[b]]);
            #pragma unroll
            for (int b = 0; b < 8; ++b)
                __builtin_nontemporal_store(m[b], &packed[i + b * stride]);
            i += 8 * stride;
        }
        for (; i < M; i += stride) {
            int e = __builtin_nontemporal_load(&aeid[i]);
            __builtin_nontemporal_store(__builtin_nontemporal_load(&meta[e]),
                                        &packed[i]);
        }
    }
}

// ---------------- all-slice edge pass (4 qs in one launch) -----------------
// q = blockIdx/nblk. One wave per node, 4 waves/block.
// lane = (g = lane>>1, h = lane&1). Anchor k = i*32+g (i=0..1);
// lane covers dims q*16 + h*8 .. +7 via ONE NT dwordx4 u-gather + v-gather.
// NT: these gathers have zero L1 reuse (random over 3.2MB) but full L2 reuse
// -> bypass L1 to dodge the 4cyc/line fill path.
template<bool GATHER>
__global__ __launch_bounds__(256) void pgnn_pass4_kernel(
    const __half* __restrict__ uvT,
    const int*    __restrict__ src,
    const int*    __restrict__ dst,
    const float*  __restrict__ sp_dist,
    const int*    __restrict__ aeid,
    const unsigned long long* __restrict__ packed,
    const float*  __restrict__ W_out,
    float* __restrict__ out_pos,     // [N,64], pre-initialized to b_out
    float* __restrict__ out_struct,  // [N,64]
    int N, int nblk)
{
    const int q   = blockIdx.x / nblk;       // 0..3
    const int blk = blockIdx.x - q * nblk;
    const int lane = threadIdx.x & 63;
    const int wv   = threadIdx.x >> 6;
    const int n    = blk * 4 + wv;
    if (n >= N) return;   // wave-uniform

    __shared__ float posb[4][64];
    float* pb = posb[wv];

    const int g = lane >> 1, h = lane & 1;

    int ms, md; float msp;
    if constexpr (GATHER) {
        const int e = __builtin_nontemporal_load(&aeid[(size_t)n * KANCH + lane]);
        ms = src[e]; md = dst[e]; msp = sp_dist[e];
    } else {
        unsigned long long pk =
            __builtin_nontemporal_load(&packed[(size_t)n * KANCH + lane]);
        unsigned lo = (unsigned)pk, hi = (unsigned)(pk >> 32);
        ms = (int)(lo & 0x1FFFFu);
        md = (int)(((lo >> 17) | (hi << 15)) & 0x1FFFFu);
        msp = __half2float(__ushort_as_half((unsigned short)((hi >> 2) & 0xFFFFu)));
    }

    const float4 wa = *reinterpret_cast<const float4*>(&W_out[q * 16 + h * 8]);
    const float4 wb = *reinterpret_cast<const float4*>(&W_out[q * 16 + h * 8 + 4]);

    const __half* Uq = uvT + (size_t)q * N * 32;

    float sacc[8];
    #pragma unroll
    for (int j = 0; j < 8; ++j) sacc[j] = 0.f;

    union H8 { vuint4 u4; __half2 h2[4]; };

    #pragma unroll
    for (int i = 0; i < 2; ++i) {
        const int k = i * 32 + g;
        const int   ss = __shfl(ms, k);
        const int   dd = __shfl(md, k);
        const float sp = __shfl(msp, k);

        H8 uu, vv;
        uu.u4 = __builtin_nontemporal_load(
            reinterpret_cast<const vuint4*>(&Uq[(size_t)ss * 32 + h * 8]));
        vv.u4 = __builtin_nontemporal_load(
            reinterpret_cast<const vuint4*>(&Uq[(size_t)dd * 32 + 16 + h * 8]));

        float m[8];
        #pragma unroll
        for (int j2 = 0; j2 < 4; ++j2) {
            float2 uf = __half22float2(uu.h2[j2]);
            float2 vf = __half22float2(vv.h2[j2]);
            m[2 * j2]     = fmaxf(fmaf(uf.x, sp, vf.x), 0.f);
            m[2 * j2 + 1] = fmaxf(fmaf(uf.y, sp, vf.y), 0.f);
        }
        #pragma unroll
        for (int j = 0; j < 8; ++j) sacc[j] += m[j];

        float p = fmaf(m[0], wa.x, fmaf(m[1], wa.y, fmaf(m[2], wa.z,
                  fmaf(m[3], wa.w, fmaf(m[4], wb.x, fmaf(m[5], wb.y,
                  fmaf(m[6], wb.z, m[7] * wb.w)))))));
        p += __shfl_xor(p, 1);
        if (h == 0) pb[k] = p;
    }
    asm volatile("s_waitcnt lgkmcnt(0)" ::: "memory");

    atomicAdd(&out_pos[(size_t)n * KANCH + lane], pb[lane]);

    #pragma unroll
    for (int off = 2; off <= 32; off <<= 1)
        #pragma unroll
        for (int j = 0; j < 8; ++j)
            sacc[j] += __shfl_xor(sacc[j], off);

    if (lane < 2) {
        const float r = 1.f / (float)KANCH;
        vfloat4 s0 = { sacc[0] * r, sacc[1] * r, sacc[2] * r, sacc[3] * r };
        vfloat4 s1 = { sacc[4] * r, sacc[5] * r, sacc[6] * r, sacc[7] * r };
        float* op = &out_struct[(size_t)n * OUT_DIM + q * 16 + h * 8];
        __builtin_nontemporal_store(s0, reinterpret_cast<vfloat4*>(op));
        __builtin_nontemporal_store(s1, reinterpret_cast<vfloat4*>(op + 4));
    }
}

extern "C" void kernel_launch(void* const* d_in, const int* in_sizes, int n_in,
                              void* d_out, int out_size, void* d_ws, size_t ws_size,
                              hipStream_t stream) {
    const float* feature    = (const float*)d_in[0];
    const int*   src        = (const int*)  d_in[1];
    const int*   dst        = (const int*)  d_in[2];
    const float* sp_dist    = (const float*)d_in[3];
    const int*   anchor_eid = (const int*)  d_in[4];
    // d_in[5] = dists_max: shape-only, numerically unused.
    const float* W_u   = (const float*)d_in[6];
    const float* b_u   = (const float*)d_in[7];
    const float* W_v   = (const float*)d_in[8];
    const float* b_v   = (const float*)d_in[9];
    const float* W_out = (const float*)d_in[10];
    const float* b_out = (const float*)d_in[11];

    const int N = in_sizes[0] / IN_DIM;           // 50000
    const int E = in_sizes[1];                    // 3.2M
    const int M = N * KANCH;

    __half* uvT = (__half*)d_ws;                  // [4][N][32] fp16, 12.8 MB
    size_t uvT_bytes  = (size_t)N * 128 * sizeof(__half);
    size_t packed_off = (uvT_bytes + 255) & ~(size_t)255;
    size_t meta_off   = (packed_off + (size_t)M * 8 + 255) & ~(size_t)255;
    unsigned long long* packed = (unsigned long long*)((char*)d_ws + packed_off);
    unsigned long long* meta   = (unsigned long long*)((char*)d_ws + meta_off);
    const bool fields_fit = (N < (1 << 17));
    const bool use_packed = fields_fit && (ws_size >= meta_off + (size_t)E * 8);

    float* out_pos    = (float*)d_out;            // [N,K]
    float* out_struct = (float*)d_out + (size_t)N * KANCH;

    const int projBlocks = (N + 63) / 64;         // 782
    const int nblk = (N + 3) / 4;                 // 12500
    const int initBlocks = ((M + 3) / 4 + 255) / 256;

    if (use_packed) {
        const int mergeBlocks = (E + 255) / 256;
        pgnn_merge_init_kernel<<<dim3(mergeBlocks + initBlocks), 256, 0, stream>>>(
            src, dst, sp_dist, meta, E, out_pos, b_out, M, mergeBlocks);
        const int packBlocks = 512;
        pgnn_fused_kernel<<<dim3(projBlocks + packBlocks), 256, 0, stream>>>(
            feature, W_u, b_u, W_v, b_v, uvT, anchor_eid, meta, packed,
            N, M, projBlocks, packBlocks);
        pgnn_pass4_kernel<false><<<dim3(4 * nblk), 256, 0, stream>>>(
            uvT, src, dst, sp_dist, anchor_eid, packed, W_out,
            out_pos, out_struct, N, nblk);
    } else {
        pgnn_merge_init_kernel<<<dim3(initBlocks), 256, 0, stream>>>(
            src, dst, sp_dist, meta, 0, out_pos, b_out, M, 0);
        pgnn_fused_kernel<<<dim3(projBlocks), 256, 0, stream>>>(
            feature, W_u, b_u, W_v, b_v, uvT, anchor_eid, meta, packed,
            N, M, projBlocks, 0);
        pgnn_pass4_kernel<true><<<dim3(4 * nblk), 256, 0, stream>>>(
            uvT, src, dst, sp_dist, anchor_eid, packed, W_out,
            out_pos, out_struct, N, nblk);
    }
}

// Round 16
// 207.042 us; speedup vs baseline: 2.1346x; 2.1346x over previous
//
#include <hip/hip_runtime.h>
#include <hip/hip_fp16.h>
#include <hip/hip_bf16.h>

// PGNN layer for MI355X (gfx950).
//   u = feature @ W_u + b_u ; v = feature @ W_v + b_v       [N,64] each
//   msg[e] = v[dst[e]] + u[src[e]] * sp_dist[e]
//   msgs = relu(msg[anchor_eid]) -> [N,K,64]
//   out_position = msgs @ W_out + b_out  [N,K];  out_structure = mean_k [N,64]
// N=50000, K=64, E=3.2M. d_out = out_position ++ out_structure.
//
// R16 vs R15 (evidence: both-fp8 absmax 7.8e-3 > 6.05e-3 threshold; cost
// model: 4 cyc per distinct 64B line-touch per CU, width-invariant; NT loads
// bypass L2 -> never on gathers):
//   HYBRID precision, 2 slices of 32 dims:
//     u: fp8 e4m3, 32B row (1 line)  -- error attenuated by sp in [0,1]
//     v: fp16,     64B row (1 line)  -- exact-ish (passes straight to msg)
//   touches 25.6M -> 12.8M (vs fp16 4-slice), working set 4.8MB/pass (~87%
//   L2 hit). Predicted absmax ~4-5.5e-3 (v-term removed).

#define IN_DIM 256
#define OUT_DIM 64
#define KANCH 64

typedef float vfloat4 __attribute__((ext_vector_type(4)));
typedef float vfloat2 __attribute__((ext_vector_type(2)));

// ---------------- merge + pos-init (fused launch) --------------------------
// Blocks [0, mergeBlocks): meta[i] = src|dst<<17|half(sp)<<34 (ids < 2^17).
// Blocks [mergeBlocks, ...): out_pos[0..M) = b_out[0].
__global__ __launch_bounds__(256) void pgnn_merge_init_kernel(
    const int* __restrict__ src, const int* __restrict__ dst,
    const float* __restrict__ sp, unsigned long long* __restrict__ meta, int E,
    float* __restrict__ out_pos, const float* __restrict__ b_out, int M,
    int mergeBlocks)
{
    if ((int)blockIdx.x < mergeBlocks) {
        int i = blockIdx.x * 256 + threadIdx.x;
        if (i >= E) return;
        unsigned long long pk =
              (unsigned long long)(unsigned)__builtin_nontemporal_load(&src[i])
            | ((unsigned long long)(unsigned)__builtin_nontemporal_load(&dst[i]) << 17)
            | ((unsigned long long)__half_as_ushort(
                   __float2half_rn(__builtin_nontemporal_load(&sp[i]))) << 34);
        __builtin_nontemporal_store(pk, &meta[i]);
    } else {
        const float bo = b_out[0];
        int i4 = (blockIdx.x - mergeBlocks) * 256 + threadIdx.x;
        int base = i4 * 4;
        if (base + 3 < M) {
            vfloat4 s = {bo, bo, bo, bo};
            __builtin_nontemporal_store(s, reinterpret_cast<vfloat4*>(&out_pos[base]));
        } else {
            for (int i = base; i < M; ++i) out_pos[i] = bo;
        }
    }
}

// ---------------- fused: proj GEMM (dbuf) + pack ---------------------------
// Blocks [0, projBlocks): proj tile BM=64 ->
//   uq8 [2][N][32]  fp8 e4m3 u (slice q: dims 32q..+31)
//   vh16[2][N][32]  fp16     v (slice q: dims 32q..+31)
// Blocks [projBlocks, ...): grid-stride pack packed[i] = meta[aeid[i]] (x8,
// PLAIN meta loads - NT bypasses L2 and regressed in R14).
#define PAa 68
#define PBb 132
#define TILEF (16 * PAa + 16 * PBb)   // floats per buffer = 3200
__global__ __launch_bounds__(256) void pgnn_fused_kernel(
    const float* __restrict__ feature,
    const float* __restrict__ Wu, const float* __restrict__ bu,
    const float* __restrict__ Wv, const float* __restrict__ bv,
    unsigned char* __restrict__ uq8,
    __half* __restrict__ vh16,
    const int* __restrict__ aeid,
    const unsigned long long* __restrict__ meta,
    unsigned long long* __restrict__ packed,
    int N, int M, int projBlocks, int packBlocks)
{
    __shared__ float smem[2 * TILEF];
    const int tid = threadIdx.x;

    if ((int)blockIdx.x < projBlocks) {
        const int row0 = blockIdx.x * 64;
        const int tr = tid >> 4;     // 0..15 -> rows tr*4..+3
        const int tc = tid & 15;     // 0..15 -> col quads (u: tc*4, v: 64+tc*4)
        const int mA = tid >> 2, c4A = tid & 3;
        const int grA = row0 + mA;

        float accU[4][4], accV[4][4];
        #pragma unroll
        for (int i = 0; i < 4; ++i)
            #pragma unroll
            for (int j = 0; j < 4; ++j) { accU[i][j] = 0.f; accV[i][j] = 0.f; }

        float4 ra, rb0, rb1;
        auto load_tile = [&](int k0) {
            ra = make_float4(0.f, 0.f, 0.f, 0.f);
            if (grA < N)
                ra = *reinterpret_cast<const float4*>(
                        &feature[(size_t)grA * IN_DIM + k0 + c4A * 4]);
            {
                int f = tid, kk = f >> 5, c4 = f & 31;
                rb0 = (c4 < 16)
                    ? *reinterpret_cast<const float4*>(&Wu[(k0 + kk) * OUT_DIM + c4 * 4])
                    : *reinterpret_cast<const float4*>(&Wv[(k0 + kk) * OUT_DIM + (c4 - 16) * 4]);
            }
            {
                int f = tid + 256, kk = f >> 5, c4 = f & 31;
                rb1 = (c4 < 16)
                    ? *reinterpret_cast<const float4*>(&Wu[(k0 + kk) * OUT_DIM + c4 * 4])
                    : *reinterpret_cast<const float4*>(&Wv[(k0 + kk) * OUT_DIM + (c4 - 16) * 4]);
            }
        };
        auto store_tile = [&](float* buf) {
            buf[(c4A * 4 + 0) * PAa + mA] = ra.x;
            buf[(c4A * 4 + 1) * PAa + mA] = ra.y;
            buf[(c4A * 4 + 2) * PAa + mA] = ra.z;
            buf[(c4A * 4 + 3) * PAa + mA] = ra.w;
            float* sB = buf + 16 * PAa;
            {
                int f = tid, kk = f >> 5, c4 = f & 31;
                *reinterpret_cast<float4*>(&sB[kk * PBb + c4 * 4]) = rb0;
            }
            {
                int f = tid + 256, kk = f >> 5, c4 = f & 31;
                *reinterpret_cast<float4*>(&sB[kk * PBb + c4 * 4]) = rb1;
            }
        };

        load_tile(0);
        store_tile(smem);
        __syncthreads();

        for (int s = 0; s < 16; ++s) {
            const int cur = s & 1;
            if (s < 15) load_tile((s + 1) * 16);
            const float* buf = smem + cur * TILEF;
            const float* sB  = buf + 16 * PAa;
            #pragma unroll
            for (int k = 0; k < 16; ++k) {
                float4 a  = *reinterpret_cast<const float4*>(&buf[k * PAa + tr * 4]);
                float4 b0 = *reinterpret_cast<const float4*>(&sB[k * PBb + tc * 4]);
                float4 b1 = *reinterpret_cast<const float4*>(&sB[k * PBb + 64 + tc * 4]);
                float av[4]  = {a.x, a.y, a.z, a.w};
                float bu4[4] = {b0.x, b0.y, b0.z, b0.w};
                float bv4[4] = {b1.x, b1.y, b1.z, b1.w};
                #pragma unroll
                for (int i = 0; i < 4; ++i)
                    #pragma unroll
                    for (int j = 0; j < 4; ++j) {
                        accU[i][j] = fmaf(av[i], bu4[j], accU[i][j]);
                        accV[i][j] = fmaf(av[i], bv4[j], accV[i][j]);
                    }
            }
            if (s < 15) store_tile(smem + (cur ^ 1) * TILEF);
            __syncthreads();
        }

        // Epilogue: bias; u -> fp8 (HW pack), v -> fp16. Slice qs = tc>>3.
        const int qs   = tc >> 3;
        const int offq = (tc & 7) * 4;     // dim offset within 32-dim slice
        float bU[4], bV[4];
        #pragma unroll
        for (int j = 0; j < 4; ++j) { bU[j] = bu[tc * 4 + j]; bV[j] = bv[tc * 4 + j]; }
        #pragma unroll
        for (int i = 0; i < 4; ++i) {
            int gr = row0 + tr * 4 + i;
            if (gr >= N) continue;
            unsigned char* urow = uq8 + ((size_t)qs * N + gr) * 32;
            int pu = 0;
            pu = __builtin_amdgcn_cvt_pk_fp8_f32(accU[i][0] + bU[0],
                                                 accU[i][1] + bU[1], pu, false);
            pu = __builtin_amdgcn_cvt_pk_fp8_f32(accU[i][2] + bU[2],
                                                 accU[i][3] + bU[3], pu, true);
            *reinterpret_cast<unsigned int*>(urow + offq) = (unsigned)pu;

            __half* vrow = vh16 + ((size_t)qs * N + gr) * 32;
            __half2 hv0 = __floats2half2_rn(accV[i][0] + bV[0], accV[i][1] + bV[1]);
            __half2 hv1 = __floats2half2_rn(accV[i][2] + bV[2], accV[i][3] + bV[3]);
            *reinterpret_cast<__half2*>(vrow + offq)     = hv0;
            *reinterpret_cast<__half2*>(vrow + offq + 2) = hv1;
        }
    } else {
        const int stride = packBlocks * 256;
        int i = (blockIdx.x - projBlocks) * 256 + tid;
        while (i + 7 * stride < M) {
            int e[8];
            #pragma unroll
            for (int b = 0; b < 8; ++b)
                e[b] = __builtin_nontemporal_load(&aeid[i + b * stride]);
            unsigned long long m[8];
            #pragma unroll
            for (int b = 0; b < 8; ++b) m[b] = meta[e[b]];   // PLAIN (L2)
            #pragma unroll
            for (int b = 0; b < 8; ++b)
                __builtin_nontemporal_store(m[b], &packed[i + b * stride]);
            i += 8 * stride;
        }
        for (; i < M; i += stride) {
            int e = __builtin_nontemporal_load(&aeid[i]);
            __builtin_nontemporal_store(meta[e], &packed[i]);
        }
    }
}

// ---------------- 2-slice edge pass (u fp8 + v fp16) -----------------------
// q = blockIdx/nblk (0..1: dims q*32..+31). One wave per node, 4 waves/block.
// lane = (g = lane>>2 anchor-group 0..15, j = lane&3 dim-octet).
// Anchor k = i*16+g (i=0..3): u = 8B fp8 octet of row ss (4 lanes share the
// 32B row = 1 line), v = 16B fp16 octet of row dd (4 lanes share 64B row).
// 2 line-touches per anchor per slice x 2 slices = 12.8M total.
template<bool GATHER>
__global__ __launch_bounds__(256) void pgnn_pass2_kernel(
    const unsigned char* __restrict__ uq8,
    const __half* __restrict__ vh16,
    const int*    __restrict__ src,
    const int*    __restrict__ dst,
    const float*  __restrict__ sp_dist,
    const int*    __restrict__ aeid,
    const unsigned long long* __restrict__ packed,
    const float*  __restrict__ W_out,
    float* __restrict__ out_pos,     // [N,64], pre-initialized to b_out
    float* __restrict__ out_struct,  // [N,64]
    int N, int nblk)
{
    const int q   = blockIdx.x / nblk;       // 0..1
    const int blk = blockIdx.x - q * nblk;
    const int lane = threadIdx.x & 63;
    const int wv   = threadIdx.x >> 6;
    const int n    = blk * 4 + wv;
    if (n >= N) return;   // wave-uniform

    __shared__ float posb[4][64];
    float* pb = posb[wv];

    const int j = lane & 3, g = lane >> 2;

    int ms, md; float msp;
    if constexpr (GATHER) {
        const int e = __builtin_nontemporal_load(&aeid[(size_t)n * KANCH + lane]);
        ms = src[e]; md = dst[e]; msp = sp_dist[e];
    } else {
        unsigned long long pk =
            __builtin_nontemporal_load(&packed[(size_t)n * KANCH + lane]);
        unsigned lo = (unsigned)pk, hi = (unsigned)(pk >> 32);
        ms = (int)(lo & 0x1FFFFu);
        md = (int)(((lo >> 17) | (hi << 15)) & 0x1FFFFu);
        msp = __half2float(__ushort_as_half((unsigned short)((hi >> 2) & 0xFFFFu)));
    }

    // W_out dims q*32 + j*8 .. +7
    float w[8];
    {
        const float* Wq = &W_out[q * 32 + j * 8];
        float4 w0 = *reinterpret_cast<const float4*>(Wq);
        float4 w1 = *reinterpret_cast<const float4*>(Wq + 4);
        w[0] = w0.x; w[1] = w0.y; w[2] = w0.z; w[3] = w0.w;
        w[4] = w1.x; w[5] = w1.y; w[6] = w1.z; w[7] = w1.w;
    }

    const unsigned char* Uq = uq8  + (size_t)q * N * 32;
    const __half*        Vq = vh16 + (size_t)q * N * 32;

    float sacc[8];
    #pragma unroll
    for (int jj = 0; jj < 8; ++jj) sacc[jj] = 0.f;

    #pragma unroll
    for (int i = 0; i < 4; ++i) {
        const int k = i * 16 + g;
        const int   ss = __shfl(ms, k);
        const int   dd = __shfl(md, k);
        const float sp = __shfl(msp, k);

        uint2 uu = *reinterpret_cast<const uint2*>(Uq + (size_t)ss * 32 + j * 8);
        uint4 vv = *reinterpret_cast<const uint4*>(
                       reinterpret_cast<const unsigned char*>(Vq) +
                       (size_t)dd * 64 + j * 16);

        float uf[8], vf[8];
        {
            vfloat2 a0 = __builtin_amdgcn_cvt_pk_f32_fp8((int)uu.x, false);
            vfloat2 a1 = __builtin_amdgcn_cvt_pk_f32_fp8((int)uu.x, true);
            vfloat2 a2 = __builtin_amdgcn_cvt_pk_f32_fp8((int)uu.y, false);
            vfloat2 a3 = __builtin_amdgcn_cvt_pk_f32_fp8((int)uu.y, true);
            uf[0] = a0.x; uf[1] = a0.y; uf[2] = a1.x; uf[3] = a1.y;
            uf[4] = a2.x; uf[5] = a2.y; uf[6] = a3.x; uf[7] = a3.y;
        }
        {
            const unsigned* vp = &vv.x;
            #pragma unroll
            for (int t = 0; t < 4; ++t) {
                __half2 h2 = *reinterpret_cast<const __half2*>(&vp[t]);
                float2 f2 = __half22float2(h2);
                vf[2 * t] = f2.x; vf[2 * t + 1] = f2.y;
            }
        }

        float m[8];
        #pragma unroll
        for (int jj = 0; jj < 8; ++jj) {
            m[jj] = fmaxf(fmaf(uf[jj], sp, vf[jj]), 0.f);
            sacc[jj] += m[jj];
        }

        float p = 0.f;
        #pragma unroll
        for (int jj = 0; jj < 8; ++jj) p = fmaf(m[jj], w[jj], p);
        p += __shfl_xor(p, 1);
        p += __shfl_xor(p, 2);          // sum over the 4-lane quad
        if (j == 0) pb[k] = p;
    }
    asm volatile("s_waitcnt lgkmcnt(0)" ::: "memory");

    atomicAdd(&out_pos[(size_t)n * KANCH + lane], pb[lane]);

    // struct: reduce sacc over the 16 g-groups (lane bits 2..5).
    #pragma unroll
    for (int off = 4; off <= 32; off <<= 1)
        #pragma unroll
        for (int jj = 0; jj < 8; ++jj)
            sacc[jj] += __shfl_xor(sacc[jj], off);

    if (lane < 4) {   // lane j holds dims q*32 + j*8 .. +7
        const float r = 1.f / (float)KANCH;
        float* op = &out_struct[(size_t)n * OUT_DIM + q * 32 + lane * 8];
        vfloat4 s0 = { sacc[0] * r, sacc[1] * r, sacc[2] * r, sacc[3] * r };
        vfloat4 s1 = { sacc[4] * r, sacc[5] * r, sacc[6] * r, sacc[7] * r };
        __builtin_nontemporal_store(s0, reinterpret_cast<vfloat4*>(op));
        __builtin_nontemporal_store(s1, reinterpret_cast<vfloat4*>(op + 4));
    }
}

extern "C" void kernel_launch(void* const* d_in, const int* in_sizes, int n_in,
                              void* d_out, int out_size, void* d_ws, size_t ws_size,
                              hipStream_t stream) {
    const float* feature    = (const float*)d_in[0];
    const int*   src        = (const int*)  d_in[1];
    const int*   dst        = (const int*)  d_in[2];
    const float* sp_dist    = (const float*)d_in[3];
    const int*   anchor_eid = (const int*)  d_in[4];
    // d_in[5] = dists_max: shape-only, numerically unused.
    const float* W_u   = (const float*)d_in[6];
    const float* b_u   = (const float*)d_in[7];
    const float* W_v   = (const float*)d_in[8];
    const float* b_v   = (const float*)d_in[9];
    const float* W_out = (const float*)d_in[10];
    const float* b_out = (const float*)d_in[11];

    const int N = in_sizes[0] / IN_DIM;           // 50000
    const int E = in_sizes[1];                    // 3.2M
    const int M = N * KANCH;

    unsigned char* uq8 = (unsigned char*)d_ws;    // [2][N][32] fp8, 3.2 MB
    size_t uq8_bytes  = (size_t)N * 64;
    size_t vh_off     = (uq8_bytes + 255) & ~(size_t)255;
    __half* vh16      = (__half*)((char*)d_ws + vh_off);   // [2][N][32] fp16, 6.4 MB
    size_t vh_bytes   = (size_t)N * 64 * sizeof(__half);
    size_t packed_off = (vh_off + vh_bytes + 255) & ~(size_t)255;
    size_t meta_off   = (packed_off + (size_t)M * 8 + 255) & ~(size_t)255;
    unsigned long long* packed = (unsigned long long*)((char*)d_ws + packed_off);
    unsigned long long* meta   = (unsigned long long*)((char*)d_ws + meta_off);
    const bool fields_fit = (N < (1 << 17));
    const bool use_packed = fields_fit && (ws_size >= meta_off + (size_t)E * 8);

    float* out_pos    = (float*)d_out;            // [N,K]
    float* out_struct = (float*)d_out + (size_t)N * KANCH;

    const int projBlocks = (N + 63) / 64;         // 782
    const int nblk = (N + 3) / 4;                 // 12500
    const int initBlocks = ((M + 3) / 4 + 255) / 256;

    if (use_packed) {
        const int mergeBlocks = (E + 255) / 256;
        pgnn_merge_init_kernel<<<dim3(mergeBlocks + initBlocks), 256, 0, stream>>>(
            src, dst, sp_dist, meta, E, out_pos, b_out, M, mergeBlocks);
        const int packBlocks = 512;
        pgnn_fused_kernel<<<dim3(projBlocks + packBlocks), 256, 0, stream>>>(
            feature, W_u, b_u, W_v, b_v, uq8, vh16, anchor_eid, meta, packed,
            N, M, projBlocks, packBlocks);
        pgnn_pass2_kernel<false><<<dim3(2 * nblk), 256, 0, stream>>>(
            uq8, vh16, src, dst, sp_dist, anchor_eid, packed, W_out,
            out_pos, out_struct, N, nblk);
    } else {
        pgnn_merge_init_kernel<<<dim3(initBlocks), 256, 0, stream>>>(
            src, dst, sp_dist, meta, 0, out_pos, b_out, M, 0);
        pgnn_fused_kernel<<<dim3(projBlocks), 256, 0, stream>>>(
            feature, W_u, b_u, W_v, b_v, uq8, vh16, anchor_eid, meta, packed,
            N, M, projBlocks, 0);
        pgnn_pass2_kernel<true><<<dim3(2 * nblk), 256, 0, stream>>>(
            uq8, vh16, src, dst, sp_dist, anchor_eid, packed, W_out,
            out_pos, out_struct, N, nblk);
    }
}